// Round 7
// baseline (450.024 us; speedup 1.0000x reference)
//
#include <hip/hip_runtime.h>

// SCN InputLayer mode=3: dedupe 24-bit voxel keys (64^4 keyspace), scatter-add
// features into sorted-unique rank order.
//   bitmap presence + popcount prefix-sum -> rank(key) = sorted-unique index.
//   atomicOr return -> "winner" point per voxel: winners plain-store (97%),
//   losers (compacted list, ~3%) atomicAdd in a later dispatch, tail rows zeroed.
// Streaming operands use nontemporal loads/stores so the 4MB meta table and
// 4MB keys stay L2-resident for the random lookups.

constexpr int S = 64;
constexpr int KEYSPACE = S * S * S * S;      // 16,777,216
constexpr int NWORDS   = KEYSPACE / 32;      // 524,288 bitmap words (2 MB)
constexpr int SCAN_BLK = 256;
constexpr int NSCANBLK = NWORDS / SCAN_BLK;  // 2048

typedef float f4 __attribute__((ext_vector_type(4)));
typedef int   i4 __attribute__((ext_vector_type(4)));

// Phase 1: mark presence; record per-point key + win flag (bit 31); compact
// the losers into a list via wave ballot (one atomic per wave).
__global__ void k_setbits(const i4* __restrict__ coords,
                          unsigned* __restrict__ bitmap,
                          unsigned* __restrict__ keys,
                          unsigned* __restrict__ loserList,
                          unsigned* __restrict__ ctr, int n) {
    int i = blockIdx.x * blockDim.x + threadIdx.x;
    bool valid = i < n;
    bool loser = false;
    if (valid) {
        i4 c = __builtin_nontemporal_load(&coords[i]);
        unsigned key = (unsigned)(((c[0] * S + c[1]) * S + c[2]) * S + c[3]);
        unsigned bit = 1u << (key & 31);
        unsigned old = atomicOr(&bitmap[key >> 5], bit);
        bool win = !(old & bit);
        loser = !win;
        keys[i] = key | (win ? 0x80000000u : 0u);
    }
    // wave-compact losers (all 64 lanes reach here; no early returns)
    unsigned lane = threadIdx.x & 63u;
    unsigned long long mask = __ballot(loser);
    unsigned count = (unsigned)__popcll(mask);
    unsigned base = 0;
    if (lane == 0 && count) base = atomicAdd(ctr, count);
    base = __shfl(base, 0);
    if (loser) {
        unsigned pre = (unsigned)__popcll(mask & ((1ull << lane) - 1ull));
        loserList[base + pre] = (unsigned)i;
    }
}

// Phase 2a: per-256-word popcount block sums.
__global__ void k_blocksums(const unsigned* __restrict__ bitmap,
                            unsigned* __restrict__ blockSums) {
    int w = blockIdx.x * SCAN_BLK + threadIdx.x;
    unsigned pc = __popc(bitmap[w]);
    for (int off = 32; off > 0; off >>= 1) pc += __shfl_down(pc, off);
    __shared__ unsigned sm[SCAN_BLK / 64];
    if ((threadIdx.x & 63) == 0) sm[threadIdx.x >> 6] = pc;
    __syncthreads();
    if (threadIdx.x == 0) {
        unsigned s = 0;
        for (int j = 0; j < SCAN_BLK / 64; ++j) s += sm[j];
        blockSums[blockIdx.x] = s;
    }
}

// Phase 2b: exclusive scan of 2048 block sums (shuffle-based); emit total.
__global__ void k_scan(const unsigned* __restrict__ blockSums,
                       unsigned* __restrict__ blockOffs,
                       unsigned* __restrict__ d_total) {
    int t = threadIdx.x;
    unsigned lane = t & 63u;
    int wave = t >> 6;
    unsigned v[8];
    unsigned s = 0;
    for (int j = 0; j < 8; ++j) { v[j] = blockSums[t * 8 + j]; s += v[j]; }
    // wave-inclusive scan of thread sums
    unsigned inc = s;
    for (int off = 1; off < 64; off <<= 1) {
        unsigned x = __shfl_up(inc, off);
        if (lane >= off) inc += x;
    }
    __shared__ unsigned wtot[4];
    if (lane == 63) wtot[wave] = inc;
    __syncthreads();
    unsigned wbase = 0;
    for (int j = 0; j < wave; ++j) wbase += wtot[j];
    unsigned excl = wbase + inc - s;         // exclusive prefix for this thread
    for (int j = 0; j < 8; ++j) { blockOffs[t * 8 + j] = excl; excl += v[j]; }
    if (t == 0) d_total[0] = wtot[0] + wtot[1] + wtot[2] + wtot[3];
}

// Phase 2c: per-word prefix via shuffle scan; pack {bits, prefix} -> uint2.
__global__ void k_meta(const unsigned* __restrict__ bitmap,
                       const unsigned* __restrict__ blockOffs,
                       uint2* __restrict__ meta) {
    int t = threadIdx.x;
    int w = blockIdx.x * SCAN_BLK + t;
    unsigned bits = bitmap[w];
    unsigned pc = __popc(bits);
    unsigned inc = pc;
    for (int off = 1; off < 64; off <<= 1) {
        unsigned x = __shfl_up(inc, off);
        if ((t & 63) >= off) inc += x;
    }
    __shared__ unsigned wsum[SCAN_BLK / 64];
    if ((t & 63) == 63) wsum[t >> 6] = inc;
    __syncthreads();
    unsigned base = 0;
    for (int j = 0; j < (t >> 6); ++j) base += wsum[j];
    meta[w] = make_uint2(bits, blockOffs[blockIdx.x] + base + (inc - pc));
}

// Phase 3a: winners plain-store their row (covers every unique row once).
// 8 lanes per point, float4 per lane; nontemporal on the streaming operands.
__global__ void k_scatter1(const unsigned* __restrict__ keys,
                           const f4* __restrict__ feats4,
                           const uint2* __restrict__ meta,
                           f4* __restrict__ out4, int n) {
    int gid = blockIdx.x * blockDim.x + threadIdx.x;
    int i = gid >> 3;
    if (i >= n) return;
    unsigned kw = keys[i];
    if (!(kw & 0x80000000u)) return;        // loser: handled later
    unsigned key = kw & 0x00FFFFFFu;
    uint2 m = meta[key >> 5];
    unsigned rank = m.y + __popc(m.x & ((1u << (key & 31)) - 1u));
    int c4 = gid & 7;
    f4 f = __builtin_nontemporal_load(&feats4[(long long)i * 8 + c4]);
    __builtin_nontemporal_store(f, &out4[(long long)rank * 8 + c4]);
}

// Phase 3b: losers (compacted, ~3%) atomicAdd; then zero the padding tail.
__global__ void k_losers_tail(const unsigned* __restrict__ keys,
                              const float* __restrict__ feats,
                              const uint2* __restrict__ meta,
                              const unsigned* __restrict__ loserList,
                              const unsigned* __restrict__ ctr,
                              const unsigned* __restrict__ d_total,
                              float* __restrict__ out,
                              f4* __restrict__ out4, int n) {
    unsigned nLosers = ctr[0];
    int tid = blockIdx.x * blockDim.x + threadIdx.x;
    int stride = gridDim.x * blockDim.x;
    for (unsigned i = tid; i < nLosers; i += stride) {
        unsigned idx = loserList[i];
        unsigned key = keys[idx] & 0x00FFFFFFu;
        uint2 m = meta[key >> 5];
        unsigned rank = m.y + __popc(m.x & ((1u << (key & 31)) - 1u));
        const float* f = feats + (long long)idx * 32;
        float* o = out + (long long)rank * 32;
#pragma unroll
        for (int c = 0; c < 32; ++c) atomicAdd(&o[c], f[c]);
    }
    // tail zero: rows [nUnique, n) x 8 float4
    unsigned nU = d_total[0];
    long long start = (long long)nU * 8;
    long long end   = (long long)n * 8;
    for (long long idx = start + tid; idx < end; idx += stride) {
        f4 z = {0.f, 0.f, 0.f, 0.f};
        __builtin_nontemporal_store(z, &out4[idx]);
    }
}

extern "C" void kernel_launch(void* const* d_in, const int* in_sizes, int n_in,
                              void* d_out, int out_size, void* d_ws, size_t ws_size,
                              hipStream_t stream) {
    const i4*    coords = (const i4*)d_in[0];
    const float* feats  = (const float*)d_in[1];
    const f4*    feats4 = (const f4*)d_in[1];
    float* out  = (float*)d_out;
    f4*    out4 = (f4*)d_out;
    int n = in_sizes[0] / 4;
    if (n <= 0) return;

    // ws layout (u32): ctr[2] | bitmap[NWORDS] | meta[2*NWORDS] | keys[n] |
    //                  loserList[n] | blockSums[NSCANBLK] | blockOffs[NSCANBLK] | total[1]
    unsigned* ctr       = (unsigned*)d_ws;
    unsigned* bitmap    = ctr + 2;
    uint2*    meta      = (uint2*)(bitmap + NWORDS);
    unsigned* keys      = bitmap + NWORDS + 2 * NWORDS;
    unsigned* loserList = keys + n;
    unsigned* blockSums = loserList + n;
    unsigned* blockOffs = blockSums + NSCANBLK;
    unsigned* d_total   = blockOffs + NSCANBLK;

    hipMemsetAsync(d_ws, 0, (size_t)(2 + NWORDS) * sizeof(unsigned), stream);

    k_setbits<<<(n + 255) / 256, 256, 0, stream>>>(coords, bitmap, keys,
                                                   loserList, ctr, n);
    k_blocksums<<<NSCANBLK, SCAN_BLK, 0, stream>>>(bitmap, blockSums);
    k_scan<<<1, 256, 0, stream>>>(blockSums, blockOffs, d_total);
    k_meta<<<NSCANBLK, SCAN_BLK, 0, stream>>>(bitmap, blockOffs, meta);

    long long lanes = (long long)n * 8;
    k_scatter1<<<(int)((lanes + 255) / 256), 256, 0, stream>>>(keys, feats4, meta, out4, n);
    k_losers_tail<<<256, 256, 0, stream>>>(keys, feats, meta, loserList, ctr,
                                           d_total, out, out4, n);
}

// Round 8
// 336.074 us; speedup vs baseline: 1.3391x; 1.3391x over previous
//
#include <hip/hip_runtime.h>

// SCN InputLayer mode=3: dedupe 24-bit voxel keys (64^4 keyspace), scatter-add
// features into sorted-unique rank order.
//   bitmap presence + popcount prefix-sum -> rank(key) = sorted-unique index.
//   atomicOr return -> "winner" per voxel: winners plain-store (97%); losers
//   found by a cheap full-N re-scan of the L2-resident keys[] (NO compaction:
//   a single-counter wave-compaction serialized 13k same-address atomics at
//   ~11.6 ns each = 154 us — measured round 7. Guideline 12.)
// NT loads/stores only on the big streams (feats, out) so meta/keys stay in L2.

constexpr int S = 64;
constexpr int KEYSPACE = S * S * S * S;      // 16,777,216
constexpr int NWORDS   = KEYSPACE / 32;      // 524,288 bitmap words (2 MB)
constexpr int SCAN_BLK = 256;
constexpr int NSCANBLK = NWORDS / SCAN_BLK;  // 2048

typedef float f4 __attribute__((ext_vector_type(4)));
typedef int   i4 __attribute__((ext_vector_type(4)));

// Phase 1: mark presence; record per-point key + win flag (bit 31).
// (regular loads: coords was just restored by the harness -> L2-hot)
__global__ void k_setbits(const i4* __restrict__ coords,
                          unsigned* __restrict__ bitmap,
                          unsigned* __restrict__ keys, int n) {
    int i = blockIdx.x * blockDim.x + threadIdx.x;
    if (i >= n) return;
    i4 c = coords[i];
    unsigned key = (unsigned)(((c[0] * S + c[1]) * S + c[2]) * S + c[3]);
    unsigned bit = 1u << (key & 31);
    unsigned old = atomicOr(&bitmap[key >> 5], bit);
    keys[i] = key | ((old & bit) ? 0u : 0x80000000u);  // bit31 = won the voxel
}

// Phase 2a: per-256-word popcount block sums.
__global__ void k_blocksums(const unsigned* __restrict__ bitmap,
                            unsigned* __restrict__ blockSums) {
    int w = blockIdx.x * SCAN_BLK + threadIdx.x;
    unsigned pc = __popc(bitmap[w]);
    for (int off = 32; off > 0; off >>= 1) pc += __shfl_down(pc, off);
    __shared__ unsigned sm[SCAN_BLK / 64];
    if ((threadIdx.x & 63) == 0) sm[threadIdx.x >> 6] = pc;
    __syncthreads();
    if (threadIdx.x == 0) {
        unsigned s = 0;
        for (int j = 0; j < SCAN_BLK / 64; ++j) s += sm[j];
        blockSums[blockIdx.x] = s;
    }
}

// Phase 2b: exclusive scan of 2048 block sums (shuffle-based); emit total.
__global__ void k_scan(const unsigned* __restrict__ blockSums,
                       unsigned* __restrict__ blockOffs,
                       unsigned* __restrict__ d_total) {
    int t = threadIdx.x;
    unsigned lane = t & 63u;
    int wave = t >> 6;
    unsigned v[8];
    unsigned s = 0;
    for (int j = 0; j < 8; ++j) { v[j] = blockSums[t * 8 + j]; s += v[j]; }
    unsigned inc = s;                        // wave-inclusive scan
    for (int off = 1; off < 64; off <<= 1) {
        unsigned x = __shfl_up(inc, off);
        if (lane >= off) inc += x;
    }
    __shared__ unsigned wtot[4];
    if (lane == 63) wtot[wave] = inc;
    __syncthreads();
    unsigned wbase = 0;
    for (int j = 0; j < wave; ++j) wbase += wtot[j];
    unsigned excl = wbase + inc - s;
    for (int j = 0; j < 8; ++j) { blockOffs[t * 8 + j] = excl; excl += v[j]; }
    if (t == 0) d_total[0] = wtot[0] + wtot[1] + wtot[2] + wtot[3];
}

// Phase 2c: per-word prefix via shuffle scan; pack {bits, prefix} -> uint2.
__global__ void k_meta(const unsigned* __restrict__ bitmap,
                       const unsigned* __restrict__ blockOffs,
                       uint2* __restrict__ meta) {
    int t = threadIdx.x;
    int w = blockIdx.x * SCAN_BLK + t;
    unsigned bits = bitmap[w];
    unsigned pc = __popc(bits);
    unsigned inc = pc;
    for (int off = 1; off < 64; off <<= 1) {
        unsigned x = __shfl_up(inc, off);
        if ((t & 63) >= off) inc += x;
    }
    __shared__ unsigned wsum[SCAN_BLK / 64];
    if ((t & 63) == 63) wsum[t >> 6] = inc;
    __syncthreads();
    unsigned base = 0;
    for (int j = 0; j < (t >> 6); ++j) base += wsum[j];
    meta[w] = make_uint2(bits, blockOffs[blockIdx.x] + base + (inc - pc));
}

// Phase 3a: winners plain-store their row (covers every unique row once).
// 8 lanes per point, float4 per lane; NT on the 250 MB feats/out streams.
__global__ void k_scatter1(const unsigned* __restrict__ keys,
                           const f4* __restrict__ feats4,
                           const uint2* __restrict__ meta,
                           f4* __restrict__ out4, int n) {
    int gid = blockIdx.x * blockDim.x + threadIdx.x;
    int i = gid >> 3;
    if (i >= n) return;
    unsigned kw = keys[i];
    if (!(kw & 0x80000000u)) return;        // loser: handled later
    unsigned key = kw & 0x00FFFFFFu;
    uint2 m = meta[key >> 5];
    unsigned rank = m.y + __popc(m.x & ((1u << (key & 31)) - 1u));
    int c4 = gid & 7;
    f4 f = __builtin_nontemporal_load(&feats4[(long long)i * 8 + c4]);
    __builtin_nontemporal_store(f, &out4[(long long)rank * 8 + c4]);
}

// Phase 3b: losers (~3%) atomicAdd on top of winners' stores (full-N scan of
// L2-resident keys — cheap); then zero the padding tail rows [nUnique, n).
__global__ void k_scatter2_tail(const unsigned* __restrict__ keys,
                                const float* __restrict__ feats,
                                const uint2* __restrict__ meta,
                                const unsigned* __restrict__ d_total,
                                float* __restrict__ out,
                                f4* __restrict__ out4, int n) {
    int i = blockIdx.x * blockDim.x + threadIdx.x;
    int stride = gridDim.x * blockDim.x;
    if (i < n) {
        unsigned kw = keys[i];
        if (!(kw & 0x80000000u)) {
            unsigned key = kw & 0x00FFFFFFu;
            uint2 m = meta[key >> 5];
            unsigned rank = m.y + __popc(m.x & ((1u << (key & 31)) - 1u));
            const float* f = feats + (long long)i * 32;
            float* o = out + (long long)rank * 32;
#pragma unroll
            for (int c = 0; c < 32; ++c) atomicAdd(&o[c], f[c]);
        }
    }
    unsigned nU = d_total[0];
    long long start = (long long)nU * 8;
    long long end   = (long long)n * 8;
    for (long long idx = start + i; idx < end; idx += stride) {
        f4 z = {0.f, 0.f, 0.f, 0.f};
        __builtin_nontemporal_store(z, &out4[idx]);
    }
}

extern "C" void kernel_launch(void* const* d_in, const int* in_sizes, int n_in,
                              void* d_out, int out_size, void* d_ws, size_t ws_size,
                              hipStream_t stream) {
    const i4*    coords = (const i4*)d_in[0];
    const float* feats  = (const float*)d_in[1];
    const f4*    feats4 = (const f4*)d_in[1];
    float* out  = (float*)d_out;
    f4*    out4 = (f4*)d_out;
    int n = in_sizes[0] / 4;
    if (n <= 0) return;

    // ws layout (u32): bitmap[NWORDS] | meta[2*NWORDS] | keys[n] |
    //                  blockSums[NSCANBLK] | blockOffs[NSCANBLK] | total[1]
    unsigned* bitmap    = (unsigned*)d_ws;
    uint2*    meta      = (uint2*)(bitmap + NWORDS);
    unsigned* keys      = bitmap + NWORDS + 2 * NWORDS;
    unsigned* blockSums = keys + n;
    unsigned* blockOffs = blockSums + NSCANBLK;
    unsigned* d_total   = blockOffs + NSCANBLK;

    hipMemsetAsync(bitmap, 0, (size_t)NWORDS * sizeof(unsigned), stream);

    k_setbits<<<(n + 255) / 256, 256, 0, stream>>>(coords, bitmap, keys, n);
    k_blocksums<<<NSCANBLK, SCAN_BLK, 0, stream>>>(bitmap, blockSums);
    k_scan<<<1, 256, 0, stream>>>(blockSums, blockOffs, d_total);
    k_meta<<<NSCANBLK, SCAN_BLK, 0, stream>>>(bitmap, blockOffs, meta);

    long long lanes = (long long)n * 8;
    k_scatter1<<<(int)((lanes + 255) / 256), 256, 0, stream>>>(keys, feats4, meta, out4, n);
    k_scatter2_tail<<<(n + 255) / 256, 256, 0, stream>>>(keys, feats, meta,
                                                         d_total, out, out4, n);
}